// Round 3
// baseline (217591.528 us; speedup 1.0000x reference)
//
#include <hip/hip_runtime.h>
#include <hip/hip_bf16.h>

#define TSTEPS 8192
#define HDIM   1024
#define FUT    16
#define RSLOT  2048          // rotating h-record slots (16 MB >> 4x L2)

typedef unsigned short bfu;
typedef __bf16 bf8v  __attribute__((ext_vector_type(8)));
typedef float  f32x4 __attribute__((ext_vector_type(4)));

__device__ __forceinline__ float u2lo(unsigned u){ return __uint_as_float(u << 16); }
__device__ __forceinline__ float u2hi(unsigned u){ return __uint_as_float(u & 0xffff0000u); }
__device__ __forceinline__ bfu f2bfu(float f){
  unsigned u = __float_as_uint(f);
  return (bfu)((u + 0x7fffu + ((u >> 16) & 1u)) >> 16);   // RNE
}
__device__ __forceinline__ ushort4 pack4(float4 v){
  ushort4 p; p.x = f2bfu(v.x); p.y = f2bfu(v.y); p.z = f2bfu(v.z); p.w = f2bfu(v.w); return p;
}
__device__ __forceinline__ float leaky(float v){ return v >= 0.f ? v : 0.8f * v; }
__device__ __forceinline__ float sigm(float v){ return 1.f / (1.f + expf(-v)); }

// ======== device-coherent (sc1 / MALL) primitives — no cache fences ========
__device__ __forceinline__ void vmwait(){ asm volatile("s_waitcnt vmcnt(0)" ::: "memory"); }
__device__ __forceinline__ void st1c(float* p, float v){
  asm volatile("global_store_dword %0, %1, off sc1" :: "v"(p), "v"(v) : "memory");
}
__device__ __forceinline__ void stflag(int* p, int v){
  asm volatile("global_store_dword %0, %1, off sc1" :: "v"(p), "v"(v) : "memory");
}
__device__ __forceinline__ float ld1c(const float* p){
  float v;
  asm volatile("global_load_dword %0, %1, off sc1\n\ts_waitcnt vmcnt(0)"
               : "=v"(v) : "v"(p) : "memory");
  return v;
}
__device__ __forceinline__ f32x4 ld4c(const float* p){
  f32x4 v;
  asm volatile("global_load_dwordx4 %0, %1, off sc1\n\ts_waitcnt vmcnt(0)"
               : "=v"(v) : "v"(p) : "memory");
  return v;
}
__device__ __forceinline__ int ldic(const int* p){
  int v;
  asm volatile("global_load_dword %0, %1, off sc1\n\ts_waitcnt vmcnt(0)"
               : "=v"(v) : "v"(p) : "memory");
  return v;
}
// round-2 flag poll (future_seq): lane polls flags[lane],[+64],[+128],[+192]
__device__ __forceinline__ void waitflag4(const int* p, int target){
  for (;;) {
    int v0, v1, v2, v3;
    asm volatile("global_load_dword %0, %4, off sc1\n\t"
                 "global_load_dword %1, %4, off offset:256 sc1\n\t"
                 "global_load_dword %2, %4, off offset:512 sc1\n\t"
                 "global_load_dword %3, %4, off offset:768 sc1\n\t"
                 "s_waitcnt vmcnt(0)"
                 : "=&v"(v0), "=&v"(v1), "=&v"(v2), "=&v"(v3) : "v"(p) : "memory");
    if (v0 >= target && v1 >= target && v2 >= target && v3 >= target) return;
    __builtin_amdgcn_s_sleep(1);
  }
}
// 8-counter wait: lanes 0..7 sc1-poll counters (64B apart), ballot-combine
__device__ __forceinline__ void wavewait(const int* cnt, int target, int lane){
  if (lane < 8) {
    for (;;) {
      int v = ldic(cnt + lane * 16);
      if (__builtin_popcountll(__ballot(v >= target)) == 8) break;
      __builtin_amdgcn_s_sleep(2);
    }
  }
}

// ================= persistent LSTM recurrence =================
// 256 blocks x 256 thr (1 block/CU, 0 LDS, weights in VGPRs). Wave w
// (global u = blockIdx*4+wv) owns L0 unit u and L1 unit u. Fused step t:
// layer0@t + layer1@(t-1). h exchanged via rotating 16MB record buffer:
// producer sc1-stores (coherent point), consumers PLAIN-load (local L2
// multicast; slot reuse distance 16MB guarantees stale-line eviction).
// Sync: 8 padded atomic counters, 128 waves each; waiters poll sc1.
__global__ __launch_bounds__(256, 1) void lstm_seq(
    const float* __restrict__ x,
    const float* __restrict__ Wih0, const float* __restrict__ Whh0,
    const float* __restrict__ bih0, const float* __restrict__ bhh0,
    const float* __restrict__ Wih1, const float* __restrict__ Whh1,
    const float* __restrict__ bih1, const float* __restrict__ bhh1,
    bfu* __restrict__ hsbf, float* __restrict__ hrot, int* __restrict__ cnt,
    float* __restrict__ c0s, float* __restrict__ c1s,
    float* __restrict__ h0f, float* __restrict__ h1f)
{
  const int tid  = threadIdx.x;
  const int b    = blockIdx.x;
  const int wv   = tid >> 6;
  const int lane = tid & 63;
  const int u    = (b << 2) + wv;          // unit index == global wave index

  // ---- weight preload into registers (fp32; coalesced float4 sweeps) ----
  // lane holds k = lane*4 + 256*j + m  (j=0..3, m=0..3) per gate row.
  float w0[4][16], wa[4][16], wb[4][16];   // Whh0 / Wih1 / Whh1
  float wxr[4], bs0[4], bs1[4];
  #pragma unroll
  for (int g = 0; g < 4; ++g) {
    const size_t row = (size_t)((g << 10) + u);
    #pragma unroll
    for (int j = 0; j < 4; ++j) {
      *(float4*)&w0[g][j * 4] = *(const float4*)(Whh0 + row * 1024 + j * 256 + lane * 4);
      *(float4*)&wa[g][j * 4] = *(const float4*)(Wih1 + row * 1024 + j * 256 + lane * 4);
      *(float4*)&wb[g][j * 4] = *(const float4*)(Whh1 + row * 1024 + j * 256 + lane * 4);
    }
    wxr[g] = (lane < 15) ? Wih0[row * 15 + lane] : 0.f;
    bs0[g] = bih0[row] + bhh0[row];
    bs1[g] = bih1[row] + bhh1[row];
  }
  float cc0 = 0.f, hv0 = 0.f, cc1 = 0.f, hv1 = 0.f;   // uniform across lanes

  // ---- prologue: zero record slot 0 (h0[-1], h1[-2]); post round 0 ----
  if (lane == 0) {
    st1c(hrot + u * 2, 0.f);
    st1c(hrot + u * 2 + 1, 0.f);
    vmwait();
    atomicAdd(cnt + (u & 7) * 16, 1);
  }

  for (int t = 0; t <= TSTEPS; ++t) {
    wavewait(cnt, 128 * (t + 1), lane);
    const float* rec = hrot + (size_t)(t & (RSLOT - 1)) * 2048;   // {h0[t-1], h1[t-2]}
    float4 h0r[4], h1r[4];
    #pragma unroll
    for (int j = 0; j < 4; ++j) {
      h0r[j] = *(const float4*)(rec + j * 256 + lane * 4);         // plain: L2 multicast
      h1r[j] = *(const float4*)(rec + 1024 + j * 256 + lane * 4);
    }
    float xv = (lane < 15 && t < TSTEPS) ? x[t * 15 + lane] : 0.f;

    float a0[4] = {0.f,0.f,0.f,0.f}, a1[4] = {0.f,0.f,0.f,0.f};
    #pragma unroll
    for (int j = 0; j < 4; ++j) {
      const float* h0p = (const float*)&h0r[j];
      const float* h1p = (const float*)&h1r[j];
      #pragma unroll
      for (int m = 0; m < 4; ++m) {
        float h0v = h0p[m], h1v = h1p[m];
        #pragma unroll
        for (int g = 0; g < 4; ++g) {
          a0[g] = fmaf(w0[g][j * 4 + m], h0v, a0[g]);
          a1[g] = fmaf(wa[g][j * 4 + m], h0v, a1[g]);
          a1[g] = fmaf(wb[g][j * 4 + m], h1v, a1[g]);
        }
      }
    }
    #pragma unroll
    for (int g = 0; g < 4; ++g) a0[g] = fmaf(wxr[g], xv, a0[g]);
    #pragma unroll
    for (int off = 32; off; off >>= 1) {
      #pragma unroll
      for (int g = 0; g < 4; ++g) {
        a0[g] += __shfl_xor(a0[g], off);
        a1[g] += __shfl_xor(a1[g], off);
      }
    }
    // gates (uniform on all lanes; stores from lane 0)
    float h1out = 0.f;
    if (t < TSTEPS) {
      float ii = sigm(a0[0] + bs0[0]), ff = sigm(a0[1] + bs0[1]);
      float gv = tanhf(a0[2] + bs0[2]), oo = sigm(a0[3] + bs0[3]);
      cc0 = ff * cc0 + ii * gv;
      hv0 = oo * tanhf(cc0);
    }
    if (t > 0) {
      float ii = sigm(a1[0] + bs1[0]), ff = sigm(a1[1] + bs1[1]);
      float gv = tanhf(a1[2] + bs1[2]), oo = sigm(a1[3] + bs1[3]);
      cc1 = ff * cc1 + ii * gv;
      hv1 = oo * tanhf(cc1);
      h1out = hv1;
    }
    if (lane == 0) {
      float* nrec = hrot + (size_t)((t + 1) & (RSLOT - 1)) * 2048;
      if (t < TSTEPS) st1c(nrec + u, hv0);         // h0[t]
      st1c(nrec + 1024 + u, h1out);                // h1[t-1] (0 at t==0)
      if (t > 0) hsbf[(size_t)(t - 1) * HDIM + u] = f2bfu(hv1);   // plain stream
      vmwait();                                    // h at coherent point
      atomicAdd(cnt + (u & 7) * 16, 1);            // then post
    }
  }
  if (lane == 0) {            // plain; flushed at dispatch end
    c0s[u] = cc0; h0f[u] = hv0;
    c1s[u] = cc1; h1f[u] = hv1;
  }
}

// ================= weight cast fp32 -> bf16 (lin0,lin1,W1,W2) =================
__global__ void cast_w(const float* __restrict__ linW, const float* __restrict__ W1m,
                       const float* __restrict__ W2m, bfu* __restrict__ wbf)
{
  int e4 = (blockIdx.x * 256 + threadIdx.x) * 4;   // < 4M
  int seg = e4 >> 20, off = e4 & 1048575;
  const float* src = (seg == 0) ? linW + off
                   : (seg == 1) ? linW + 1048576 + off
                   : (seg == 2) ? W1m + off : W2m + off;
  float4 v = *(const float4*)src;
  *(ushort4*)(wbf + e4) = pack4(v);
}

// ================= bf16 MFMA GEMM: Out[m][n] = leaky(sum_k A[m][k]*Bw[n][k] + bias[n]) =================
__global__ __launch_bounds__(256, 1) void mlp_gemm(
    const bfu* __restrict__ A, const bfu* __restrict__ Bw,
    const float* __restrict__ bias, bfu* __restrict__ Out)
{
  __shared__ bfu At[128 * 40];    // pitch 40 bf16 (pad)
  __shared__ bfu Bt[128 * 40];
  const int tid = threadIdx.x;
  const int bm = blockIdx.x * 128, bn = blockIdx.y * 128;
  const int wv = tid >> 6, lane = tid & 63;
  const int wm = (wv & 1) * 64, wn = (wv >> 1) * 64;
  const int m16 = lane & 15, q = lane >> 4;
  f32x4 acc[4][4];
  #pragma unroll
  for (int i = 0; i < 4; ++i)
    #pragma unroll
    for (int j = 0; j < 4; ++j) { f32x4 z = {0.f,0.f,0.f,0.f}; acc[i][j] = z; }

  for (int kt = 0; kt < 1024; kt += 32) {
    __syncthreads();
    #pragma unroll
    for (int i = 0; i < 2; ++i) {
      int idx = tid + i * 256;
      int r = idx >> 2, ch = idx & 3;
      *(uint4*)(At + r * 40 + ch * 8) = *(const uint4*)(A  + (size_t)(bm + r) * 1024 + kt + ch * 8);
      *(uint4*)(Bt + r * 40 + ch * 8) = *(const uint4*)(Bw + (size_t)(bn + r) * 1024 + kt + ch * 8);
    }
    __syncthreads();
    bf8v af[4], bfv[4];
    #pragma unroll
    for (int i = 0; i < 4; ++i) af[i]  = *(const bf8v*)(const void*)(At + (wm + i * 16 + m16) * 40 + q * 8);
    #pragma unroll
    for (int j = 0; j < 4; ++j) bfv[j] = *(const bf8v*)(const void*)(Bt + (wn + j * 16 + m16) * 40 + q * 8);
    #pragma unroll
    for (int i = 0; i < 4; ++i)
      #pragma unroll
      for (int j = 0; j < 4; ++j)
        acc[i][j] = __builtin_amdgcn_mfma_f32_16x16x32_bf16(af[i], bfv[j], acc[i][j], 0, 0, 0);
  }
  #pragma unroll
  for (int j = 0; j < 4; ++j) {
    int col = bn + wn + j * 16 + m16;
    float bv = bias[col];
    #pragma unroll
    for (int i = 0; i < 4; ++i) {
      #pragma unroll
      for (int r = 0; r < 4; ++r) {
        int row = bm + wm + i * 16 + q * 4 + r;   // C/D: col=lane&15, row=quad*4+reg
        float v = leaky(acc[i][j][r] + bv);
        Out[(size_t)row * 1024 + col] = f2bfu(v);
      }
    }
  }
}

// ================= Wo head: dout[t][o] = leaky(sum_k h[t][k]*Wo[o][k] + bo[o]) =================
__global__ void wo_ker(const bfu* __restrict__ Hb, const float* __restrict__ Wo,
                       const float* __restrict__ bo, float* __restrict__ dout,
                       float* __restrict__ outv)
{
  int tid = threadIdx.x;
  int t = blockIdx.x * 16 + (tid >> 4);
  int o = tid & 15;
  if (o == 15) return;
  const bfu* hr = Hb + (size_t)t * 1024;
  const float* wr = Wo + (size_t)o * 1024;
  float acc = 0.f;
  for (int k = 0; k < 1024; k += 8) {
    uint4 hc = *(const uint4*)(hr + k);
    float4 w0 = *(const float4*)(wr + k);
    float4 w1 = *(const float4*)(wr + k + 4);
    acc = fmaf(u2lo(hc.x), w0.x, acc); acc = fmaf(u2hi(hc.x), w0.y, acc);
    acc = fmaf(u2lo(hc.y), w0.z, acc); acc = fmaf(u2hi(hc.y), w0.w, acc);
    acc = fmaf(u2lo(hc.z), w1.x, acc); acc = fmaf(u2hi(hc.z), w1.y, acc);
    acc = fmaf(u2lo(hc.w), w1.z, acc); acc = fmaf(u2hi(hc.w), w1.w, acc);
  }
  acc = leaky(acc + bo[o]);
  dout[t * 15 + o] = acc;
  if (t == 8191) outv[o] = acc;
}

// ================= future steps (persistent, 256 blocks, 7 phases/step) =================
__device__ __forceinline__ float rowdot1024(const float* __restrict__ W,
                                            const float* __restrict__ v, int lane){
  float acc = 0.f;
  #pragma unroll
  for (int p = 0; p < 4; ++p) {
    int k = p * 256 + lane * 4;
    float4 w = *(const float4*)(W + k);
    float4 h = *(const float4*)(v + k);
    acc = fmaf(w.x, h.x, acc); acc = fmaf(w.y, h.y, acc);
    acc = fmaf(w.z, h.z, acc); acc = fmaf(w.w, h.w, acc);
  }
  #pragma unroll
  for (int off = 32; off; off >>= 1) acc += __shfl_xor(acc, off);
  return acc;
}

__global__ __launch_bounds__(256, 1) void future_seq(
    const float* __restrict__ Wih0, const float* __restrict__ Whh0,
    const float* __restrict__ bih0, const float* __restrict__ bhh0,
    const float* __restrict__ Wih1, const float* __restrict__ Whh1,
    const float* __restrict__ bih1, const float* __restrict__ bhh1,
    const float* __restrict__ linW, const float* __restrict__ linb,
    const float* __restrict__ W1m, const float* __restrict__ b1v,
    const float* __restrict__ W2m, const float* __restrict__ b2v,
    const float* __restrict__ Wo, const float* __restrict__ bo,
    float* __restrict__ h0fD, float* __restrict__ h1fD,
    const float* __restrict__ c0s, const float* __restrict__ c1s,
    float* __restrict__ v1, float* __restrict__ v2,
    float* __restrict__ v3, float* __restrict__ v4,
    float* __restrict__ outv, float* __restrict__ dout, int* __restrict__ flagD)
{
  __shared__ float vs[1024];
  __shared__ float vs2[1024];
  __shared__ float xsf[16];
  const int tid = threadIdx.x, b = blockIdx.x, wv = tid >> 6, lane = tid & 63;
  const int unit = (b << 2) + wv;
  float c0 = 0.f, c1 = 0.f;
  if (lane == 0) { c0 = c0s[unit]; c1 = c1s[unit]; }   // plain (prev dispatch)
  int pc = 0;
  for (int s = 0; s < FUT; ++s) {
    const int cur = s & 1, nxt = cur ^ 1;
    // ---- P1: layer0
    if (tid < 64) waitflag4(flagD + tid, pc);
    __syncthreads();
    ((f32x4*)vs)[tid] = ld4c(h0fD + cur * 1024 + tid * 4);
    if (tid < 15) xsf[tid] = ld1c(outv + tid);
    __syncthreads();
    float a[4];
    #pragma unroll
    for (int g = 0; g < 4; ++g)
      a[g] = rowdot1024(Whh0 + (size_t)((g << 10) + unit) * 1024, vs, lane);
    if (lane == 0) {
      float gg[4];
      #pragma unroll
      for (int g = 0; g < 4; ++g) {
        int R = (g << 10) + unit;
        float s15 = 0.f;
        for (int k = 0; k < 15; ++k) s15 = fmaf(Wih0[R * 15 + k], xsf[k], s15);
        gg[g] = a[g] + s15 + bih0[R] + bhh0[R];
      }
      float ii = sigm(gg[0]), ff = sigm(gg[1]), gv = tanhf(gg[2]), oo = sigm(gg[3]);
      c0 = ff * c0 + ii * gv;
      st1c(h0fD + nxt * 1024 + unit, oo * tanhf(c0));
      vmwait();
    }
    __syncthreads(); ++pc; if (tid == 0) stflag(flagD + b, pc);
    // ---- P2: layer1
    if (tid < 64) waitflag4(flagD + tid, pc);
    __syncthreads();
    ((f32x4*)vs)[tid]  = ld4c(h0fD + nxt * 1024 + tid * 4);
    ((f32x4*)vs2)[tid] = ld4c(h1fD + cur * 1024 + tid * 4);
    __syncthreads();
    #pragma unroll
    for (int g = 0; g < 4; ++g) {
      int R = (g << 10) + unit;
      float acc = 0.f;
      #pragma unroll
      for (int p = 0; p < 4; ++p) {
        int k = p * 256 + lane * 4;
        float4 w = *(const float4*)(Wih1 + (size_t)R * 1024 + k);
        float4 h = *(const float4*)(vs + k);
        acc = fmaf(w.x, h.x, acc); acc = fmaf(w.y, h.y, acc);
        acc = fmaf(w.z, h.z, acc); acc = fmaf(w.w, h.w, acc);
        float4 w2 = *(const float4*)(Whh1 + (size_t)R * 1024 + k);
        float4 h2 = *(const float4*)(vs2 + k);
        acc = fmaf(w2.x, h2.x, acc); acc = fmaf(w2.y, h2.y, acc);
        acc = fmaf(w2.z, h2.z, acc); acc = fmaf(w2.w, h2.w, acc);
      }
      #pragma unroll
      for (int off = 32; off; off >>= 1) acc += __shfl_xor(acc, off);
      a[g] = acc;
    }
    if (lane == 0) {
      float gg[4];
      #pragma unroll
      for (int g = 0; g < 4; ++g) { int R = (g << 10) + unit; gg[g] = a[g] + bih1[R] + bhh1[R]; }
      float ii = sigm(gg[0]), ff = sigm(gg[1]), gv = tanhf(gg[2]), oo = sigm(gg[3]);
      c1 = ff * c1 + ii * gv;
      st1c(h1fD + nxt * 1024 + unit, oo * tanhf(c1));
      vmwait();
    }
    __syncthreads(); ++pc; if (tid == 0) stflag(flagD + b, pc);
    // ---- P3..P6: dense H->H layers
    for (int l = 0; l < 4; ++l) {
      const float* Wd = (l == 0) ? linW : (l == 1) ? linW + 1048576 : (l == 2) ? W1m : W2m;
      const float* bd = (l == 0) ? linb : (l == 1) ? linb + 1024 : (l == 2) ? b1v : b2v;
      const float* vin = (l == 0) ? (h1fD + nxt * 1024) : (l == 1) ? v1 : (l == 2) ? v2 : v3;
      float* vo = (l == 0) ? v1 : (l == 1) ? v2 : (l == 2) ? v3 : v4;
      if (tid < 64) waitflag4(flagD + tid, pc);
      __syncthreads();
      ((f32x4*)vs)[tid] = ld4c(vin + tid * 4);
      __syncthreads();
      float acc = rowdot1024(Wd + (size_t)unit * 1024, vs, lane);
      if (lane == 0) { st1c(vo + unit, leaky(acc + bd[unit])); vmwait(); }
      __syncthreads(); ++pc; if (tid == 0) stflag(flagD + b, pc);
    }
    // ---- P7: Wo head
    if (tid < 64) waitflag4(flagD + tid, pc);
    __syncthreads();
    ((f32x4*)vs)[tid] = ld4c(v4 + tid * 4);
    __syncthreads();
    if (b == 0) {
      for (int o = wv; o < 15; o += 4) {
        float acc = rowdot1024(Wo + (size_t)o * 1024, vs, lane);
        if (lane == 0) {
          float r = leaky(acc + bo[o]);
          dout[(8192 + s) * 15 + o] = r;     // plain (output)
          st1c(outv + o, r);                 // coherent (consumed next step)
        }
      }
      if (lane == 0) vmwait();
    }
    __syncthreads(); ++pc; if (tid == 0) stflag(flagD + b, pc);
  }
}

// ================= host =================
extern "C" void kernel_launch(void* const* d_in, const int* in_sizes, int n_in,
                              void* d_out, int out_size, void* d_ws, size_t ws_size,
                              hipStream_t stream)
{
  (void)in_sizes; (void)n_in; (void)out_size; (void)ws_size;
  const float* x    = (const float*)d_in[0];
  const float* Wih0 = (const float*)d_in[1];
  const float* Whh0 = (const float*)d_in[2];
  const float* bih0 = (const float*)d_in[3];
  const float* bhh0 = (const float*)d_in[4];
  const float* Wih1 = (const float*)d_in[5];
  const float* Whh1 = (const float*)d_in[6];
  const float* bih1 = (const float*)d_in[7];
  const float* bhh1 = (const float*)d_in[8];
  const float* linW = (const float*)d_in[9];
  const float* linb = (const float*)d_in[10];
  const float* W1m  = (const float*)d_in[11];
  const float* b1v  = (const float*)d_in[12];
  const float* W2m  = (const float*)d_in[13];
  const float* b2v  = (const float*)d_in[14];
  const float* Wo   = (const float*)d_in[15];
  const float* bo   = (const float*)d_in[16];
  float* dout = (float*)d_out;
  char*  ws   = (char*)d_ws;

  bfu*   hsbf = (bfu*)(ws);                            // 8192x1024 bf16 (16 MB)
  bfu*   ping = (bfu*)(ws + (size_t)16777216);         // 8192x1024 bf16 (16 MB)
  bfu*   wbf  = (bfu*)(ws + (size_t)33554432);         // 4x1024x1024 bf16 (8 MB)
  float* hrot = (float*)(ws + (size_t)41943040);       // RSLOT x 2048 fp32 (16 MB)
  char*  ctrl = ws + (size_t)58720256;
  int*   cnt   = (int*)ctrl;                           // 8 counters, 64B apart (512 B)
  int*   flagD = (int*)(ctrl + 2048);                  // 256 ints
  float* c0s   = (float*)(ctrl + 4096);
  float* c1s   = (float*)(ctrl + 8192);
  float* h0fD  = (float*)(ctrl + 12288);               // 2x1024
  float* h1fD  = (float*)(ctrl + 20480);               // 2x1024
  float* v1    = (float*)(ctrl + 28672);
  float* v2    = v1 + 1024;
  float* v3    = v2 + 1024;
  float* v4    = v3 + 1024;
  float* outv  = v4 + 1024;

  hipMemsetAsync(ctrl, 0, 3072, stream);   // counters + flagD

  cast_w<<<dim3(4096), dim3(256), 0, stream>>>(linW, W1m, W2m, wbf);

  lstm_seq<<<dim3(256), dim3(256), 0, stream>>>(
      x, Wih0, Whh0, bih0, bhh0, Wih1, Whh1, bih1, bhh1,
      hsbf, hrot, cnt, c0s, c1s, h0fD, h1fD);

  dim3 gg(64, 8), bb(256);
  mlp_gemm<<<gg, bb, 0, stream>>>(hsbf, wbf,           linb,        ping);
  mlp_gemm<<<gg, bb, 0, stream>>>(ping, wbf + 1048576, linb + 1024, hsbf);
  mlp_gemm<<<gg, bb, 0, stream>>>(hsbf, wbf + 2097152, b1v,         ping);
  mlp_gemm<<<gg, bb, 0, stream>>>(ping, wbf + 3145728, b2v,         hsbf);

  wo_ker<<<dim3(512), dim3(256), 0, stream>>>(hsbf, Wo, bo, dout, outv);

  future_seq<<<dim3(256), dim3(256), 0, stream>>>(
      Wih0, Whh0, bih0, bhh0, Wih1, Whh1, bih1, bhh1,
      linW, linb, W1m, b1v, W2m, b2v, Wo, bo,
      h0fD, h1fD, c0s, c1s, v1, v2, v3, v4, outv, dout, flagD);
}

// Round 4
// 38950.513 us; speedup vs baseline: 5.5864x; 5.5864x over previous
//
#include <hip/hip_runtime.h>
#include <hip/hip_bf16.h>

#define TSTEPS 8192
#define HDIM   1024
#define FUT    16
#define RSLOT  8            // rotating h-record slots (skew bound ~2 steps; 8 is safe)

typedef unsigned short bfu;
typedef __bf16 bf8v  __attribute__((ext_vector_type(8)));
typedef float  f32x4 __attribute__((ext_vector_type(4)));
typedef int    i32x4 __attribute__((ext_vector_type(4)));
typedef int    i32x2 __attribute__((ext_vector_type(2)));

__device__ __forceinline__ float u2lo(unsigned u){ return __uint_as_float(u << 16); }
__device__ __forceinline__ float u2hi(unsigned u){ return __uint_as_float(u & 0xffff0000u); }
__device__ __forceinline__ bfu f2bfu(float f){
  unsigned u = __float_as_uint(f);
  return (bfu)((u + 0x7fffu + ((u >> 16) & 1u)) >> 16);   // RNE
}
__device__ __forceinline__ ushort4 pack4(float4 v){
  ushort4 p; p.x = f2bfu(v.x); p.y = f2bfu(v.y); p.z = f2bfu(v.z); p.w = f2bfu(v.w); return p;
}
__device__ __forceinline__ float leaky(float v){ return v >= 0.f ? v : 0.8f * v; }
__device__ __forceinline__ float sigm(float v){ return 1.f / (1.f + expf(-v)); }

// ---- tagged-pair primitives: pair = {f32 value, i32 tag}, 8B-atomic sc1 ----
__device__ __forceinline__ void st2c(void* p, float h, int tag){
  i32x2 v; v.x = __float_as_int(h); v.y = tag;
  asm volatile("global_store_dwordx2 %0, %1, off sc1" :: "v"(p), "v"(v) : "memory");
}

// stage 1024 pairs (8KB) -> vs[1024] (LDS), wave-coalesced, tag-validated.
// 256 threads: wave wv covers bytes [wv*2048, +2048) x2 (offset 1024).
__device__ __forceinline__ void stage1024(const char* buf, int want, float* vs,
                                          int wv, int lane){
  const char* base = buf + (wv << 11) + (lane << 4);
  i32x4 q0, q1;
  for (;;) {
    asm volatile(
      "global_load_dwordx4 %0, %2, off sc1\n\t"
      "global_load_dwordx4 %1, %2, off offset:1024 sc1\n\t"
      "s_waitcnt vmcnt(0)"
      : "=&v"(q0), "=&v"(q1) : "v"(base) : "memory");
    if (q0.y == want && q0.w == want && q1.y == want && q1.w == want) break;
    __builtin_amdgcn_s_sleep(2);
  }
  int idx = (wv << 8) + (lane << 1);
  float2 f0 = {__int_as_float(q0.x), __int_as_float(q0.z)};
  float2 f1 = {__int_as_float(q1.x), __int_as_float(q1.z)};
  *(float2*)(vs + idx)       = f0;
  *(float2*)(vs + idx + 128) = f1;
}

// ================= persistent LSTM recurrence =================
// 256 blocks x 256 thr (1 block/CU). Wave (global u = blockIdx*4+wv) owns L0
// unit u and L1 unit u; weights in VGPRs (fp32). Fused step t: layer0@t +
// layer1@(t-1). h exchange: rotating tagged-pair records (16KB/slot); stores
// are fire-and-forget sc1 dwordx2; consumers tag-poll. No flags, no atomics,
// no fences, no store-ack waits.
__global__ __launch_bounds__(256, 1) void lstm_seq(
    const float* __restrict__ x,
    const float* __restrict__ Wih0, const float* __restrict__ Whh0,
    const float* __restrict__ bih0, const float* __restrict__ bhh0,
    const float* __restrict__ Wih1, const float* __restrict__ Whh1,
    const float* __restrict__ bih1, const float* __restrict__ bhh1,
    bfu* __restrict__ hsbf, char* __restrict__ hrec,
    float* __restrict__ c0s, float* __restrict__ c1s,
    float* __restrict__ h0f, float* __restrict__ h1f)
{
  __shared__ float hcat[2048];       // [h0(t-1) | h1(t-2)] fp32

  const int tid  = threadIdx.x;
  const int b    = blockIdx.x;
  const int wv   = tid >> 6;
  const int lane = tid & 63;
  const int u    = (b << 2) + wv;

  // ---- weight preload into registers (fp32; coalesced float4 sweeps) ----
  float w0[4][16], wa[4][16], wb[4][16];   // Whh0 / Wih1 / Whh1
  float wxr[4], bs0[4], bs1[4];
  #pragma unroll
  for (int g = 0; g < 4; ++g) {
    const size_t row = (size_t)((g << 10) + u);
    #pragma unroll
    for (int j = 0; j < 4; ++j) {
      *(float4*)&w0[g][j * 4] = *(const float4*)(Whh0 + row * 1024 + j * 256 + lane * 4);
      *(float4*)&wa[g][j * 4] = *(const float4*)(Wih1 + row * 1024 + j * 256 + lane * 4);
      *(float4*)&wb[g][j * 4] = *(const float4*)(Whh1 + row * 1024 + j * 256 + lane * 4);
    }
    wxr[g] = (lane < 15) ? Wih0[row * 15 + lane] : 0.f;
    bs0[g] = bih0[row] + bhh0[row];
    bs1[g] = bih1[row] + bhh1[row];
  }
  float cc0 = 0.f, hv0 = 0.f, cc1 = 0.f, hv1 = 0.f;

  // ---- prologue: slot 0 = {h0[-1]=0, h1[-2]=0} tagged -1 (fire & forget) ----
  if (lane == 0) {
    st2c(hrec + u * 8, 0.f, -1);
    st2c(hrec + 8192 + u * 8, 0.f, -1);
  }

  for (int t = 0; t <= TSTEPS; ++t) {
    const char* rec = hrec + (size_t)(t & (RSLOT - 1)) * 16384;
    const int want = t - 1;
    float xv = (lane < 15 && t < TSTEPS) ? x[t * 15 + lane] : 0.f;  // early issue

    // ---- stage + validate 16KB record (wave-coalesced sc1, tag-poll) ----
    {
      const char* base = rec + (wv << 12) + (lane << 4);
      i32x4 q0, q1, q2, q3;
      for (;;) {
        asm volatile(
          "global_load_dwordx4 %0, %4, off sc1\n\t"
          "global_load_dwordx4 %1, %4, off offset:1024 sc1\n\t"
          "global_load_dwordx4 %2, %4, off offset:2048 sc1\n\t"
          "global_load_dwordx4 %3, %4, off offset:3072 sc1\n\t"
          "s_waitcnt vmcnt(0)"
          : "=&v"(q0), "=&v"(q1), "=&v"(q2), "=&v"(q3) : "v"(base) : "memory");
        if (q0.y == want && q0.w == want && q1.y == want && q1.w == want &&
            q2.y == want && q2.w == want && q3.y == want && q3.w == want) break;
        __builtin_amdgcn_s_sleep(2);
      }
      int idx = (wv << 9) + (lane << 1);
      float2 f0 = {__int_as_float(q0.x), __int_as_float(q0.z)};
      float2 f1 = {__int_as_float(q1.x), __int_as_float(q1.z)};
      float2 f2 = {__int_as_float(q2.x), __int_as_float(q2.z)};
      float2 f3 = {__int_as_float(q3.x), __int_as_float(q3.z)};
      *(float2*)(hcat + idx)       = f0;
      *(float2*)(hcat + idx + 128) = f1;
      *(float2*)(hcat + idx + 256) = f2;
      *(float2*)(hcat + idx + 384) = f3;
    }
    __syncthreads();

    float a0[4] = {0.f,0.f,0.f,0.f}, a1[4] = {0.f,0.f,0.f,0.f};
    #pragma unroll
    for (int j = 0; j < 4; ++j) {
      f32x4 h0r = *(const f32x4*)(hcat + j * 256 + lane * 4);
      f32x4 h1r = *(const f32x4*)(hcat + 1024 + j * 256 + lane * 4);
      #pragma unroll
      for (int m = 0; m < 4; ++m) {
        float h0v = h0r[m], h1v = h1r[m];
        #pragma unroll
        for (int g = 0; g < 4; ++g) {
          a0[g] = fmaf(w0[g][j * 4 + m], h0v, a0[g]);
          a1[g] = fmaf(wa[g][j * 4 + m], h0v, a1[g]);
          a1[g] = fmaf(wb[g][j * 4 + m], h1v, a1[g]);
        }
      }
    }
    #pragma unroll
    for (int g = 0; g < 4; ++g) a0[g] = fmaf(wxr[g], xv, a0[g]);
    #pragma unroll
    for (int off = 32; off; off >>= 1) {
      #pragma unroll
      for (int g = 0; g < 4; ++g) {
        a0[g] += __shfl_xor(a0[g], off);
        a1[g] += __shfl_xor(a1[g], off);
      }
    }
    float h1out = 0.f;
    if (t < TSTEPS) {
      float ii = sigm(a0[0] + bs0[0]), ff = sigm(a0[1] + bs0[1]);
      float gv = tanhf(a0[2] + bs0[2]), oo = sigm(a0[3] + bs0[3]);
      cc0 = ff * cc0 + ii * gv;
      hv0 = oo * tanhf(cc0);
    }
    if (t > 0) {
      float ii = sigm(a1[0] + bs1[0]), ff = sigm(a1[1] + bs1[1]);
      float gv = tanhf(a1[2] + bs1[2]), oo = sigm(a1[3] + bs1[3]);
      cc1 = ff * cc1 + ii * gv;
      hv1 = oo * tanhf(cc1);
      h1out = hv1;
    }
    if (lane == 0) {
      if (t < TSTEPS) {
        char* nrec = hrec + (size_t)((t + 1) & (RSLOT - 1)) * 16384;
        st2c(nrec + u * 8, hv0, t);            // h0[t], tag t — fire & forget
        st2c(nrec + 8192 + u * 8, h1out, t);   // h1[t-1], tag t
      }
      if (t > 0) hsbf[(size_t)(t - 1) * HDIM + u] = f2bfu(hv1);   // plain stream
    }
  }
  if (lane == 0) {            // plain; flushed (L2 writeback) at dispatch end
    c0s[u] = cc0; h0f[u] = hv0;
    c1s[u] = cc1; h1f[u] = hv1;
  }
}

// ================= weight cast fp32 -> bf16 (lin0,lin1,W1,W2) =================
__global__ void cast_w(const float* __restrict__ linW, const float* __restrict__ W1m,
                       const float* __restrict__ W2m, bfu* __restrict__ wbf)
{
  int e4 = (blockIdx.x * 256 + threadIdx.x) * 4;   // < 4M
  int seg = e4 >> 20, off = e4 & 1048575;
  const float* src = (seg == 0) ? linW + off
                   : (seg == 1) ? linW + 1048576 + off
                   : (seg == 2) ? W1m + off : W2m + off;
  float4 v = *(const float4*)src;
  *(ushort4*)(wbf + e4) = pack4(v);
}

// ================= bf16 MFMA GEMM: Out[m][n] = leaky(sum_k A[m][k]*Bw[n][k] + bias[n]) =================
__global__ __launch_bounds__(256, 1) void mlp_gemm(
    const bfu* __restrict__ A, const bfu* __restrict__ Bw,
    const float* __restrict__ bias, bfu* __restrict__ Out)
{
  __shared__ bfu At[128 * 40];    // pitch 40 bf16 (pad)
  __shared__ bfu Bt[128 * 40];
  const int tid = threadIdx.x;
  const int bm = blockIdx.x * 128, bn = blockIdx.y * 128;
  const int wv = tid >> 6, lane = tid & 63;
  const int wm = (wv & 1) * 64, wn = (wv >> 1) * 64;
  const int m16 = lane & 15, q = lane >> 4;
  f32x4 acc[4][4];
  #pragma unroll
  for (int i = 0; i < 4; ++i)
    #pragma unroll
    for (int j = 0; j < 4; ++j) { f32x4 z = {0.f,0.f,0.f,0.f}; acc[i][j] = z; }

  for (int kt = 0; kt < 1024; kt += 32) {
    __syncthreads();
    #pragma unroll
    for (int i = 0; i < 2; ++i) {
      int idx = tid + i * 256;
      int r = idx >> 2, ch = idx & 3;
      *(uint4*)(At + r * 40 + ch * 8) = *(const uint4*)(A  + (size_t)(bm + r) * 1024 + kt + ch * 8);
      *(uint4*)(Bt + r * 40 + ch * 8) = *(const uint4*)(Bw + (size_t)(bn + r) * 1024 + kt + ch * 8);
    }
    __syncthreads();
    bf8v af[4], bfv[4];
    #pragma unroll
    for (int i = 0; i < 4; ++i) af[i]  = *(const bf8v*)(const void*)(At + (wm + i * 16 + m16) * 40 + q * 8);
    #pragma unroll
    for (int j = 0; j < 4; ++j) bfv[j] = *(const bf8v*)(const void*)(Bt + (wn + j * 16 + m16) * 40 + q * 8);
    #pragma unroll
    for (int i = 0; i < 4; ++i)
      #pragma unroll
      for (int j = 0; j < 4; ++j)
        acc[i][j] = __builtin_amdgcn_mfma_f32_16x16x32_bf16(af[i], bfv[j], acc[i][j], 0, 0, 0);
  }
  #pragma unroll
  for (int j = 0; j < 4; ++j) {
    int col = bn + wn + j * 16 + m16;
    float bv = bias[col];
    #pragma unroll
    for (int i = 0; i < 4; ++i) {
      #pragma unroll
      for (int r = 0; r < 4; ++r) {
        int row = bm + wm + i * 16 + q * 4 + r;   // C/D: col=lane&15, row=quad*4+reg
        float v = leaky(acc[i][j][r] + bv);
        Out[(size_t)row * 1024 + col] = f2bfu(v);
      }
    }
  }
}

// ================= Wo head: dout[t][o] = leaky(sum_k h[t][k]*Wo[o][k] + bo[o]) =================
__global__ void wo_ker(const bfu* __restrict__ Hb, const float* __restrict__ Wo,
                       const float* __restrict__ bo, float* __restrict__ dout,
                       char* __restrict__ pbo)
{
  int tid = threadIdx.x;
  int t = blockIdx.x * 16 + (tid >> 4);
  int o = tid & 15;
  if (o == 15) return;
  const bfu* hr = Hb + (size_t)t * 1024;
  const float* wr = Wo + (size_t)o * 1024;
  float acc = 0.f;
  for (int k = 0; k < 1024; k += 8) {
    uint4 hc = *(const uint4*)(hr + k);
    float4 w0 = *(const float4*)(wr + k);
    float4 w1 = *(const float4*)(wr + k + 4);
    acc = fmaf(u2lo(hc.x), w0.x, acc); acc = fmaf(u2hi(hc.x), w0.y, acc);
    acc = fmaf(u2lo(hc.y), w0.z, acc); acc = fmaf(u2hi(hc.y), w0.w, acc);
    acc = fmaf(u2lo(hc.z), w1.x, acc); acc = fmaf(u2hi(hc.z), w1.y, acc);
    acc = fmaf(u2lo(hc.w), w1.z, acc); acc = fmaf(u2hi(hc.w), w1.w, acc);
  }
  acc = leaky(acc + bo[o]);
  dout[t * 15 + o] = acc;
  if (t == 8191) st2c(pbo + o * 8, acc, -1);   // seed future P1 (tag -1)
}

// ================= future steps (persistent, tag-synced, 7 phases/step) =================
__device__ __forceinline__ float rowdot1024(const float* __restrict__ W,
                                            const float* __restrict__ v, int lane){
  float acc = 0.f;
  #pragma unroll
  for (int p = 0; p < 4; ++p) {
    int k = p * 256 + lane * 4;
    float4 w = *(const float4*)(W + k);
    float4 h = *(const float4*)(v + k);
    acc = fmaf(w.x, h.x, acc); acc = fmaf(w.y, h.y, acc);
    acc = fmaf(w.z, h.z, acc); acc = fmaf(w.w, h.w, acc);
  }
  #pragma unroll
  for (int off = 32; off; off >>= 1) acc += __shfl_xor(acc, off);
  return acc;
}

__global__ __launch_bounds__(256, 1) void future_seq(
    const float* __restrict__ Wih0, const float* __restrict__ Whh0,
    const float* __restrict__ bih0, const float* __restrict__ bhh0,
    const float* __restrict__ Wih1, const float* __restrict__ Whh1,
    const float* __restrict__ bih1, const float* __restrict__ bhh1,
    const float* __restrict__ linW, const float* __restrict__ linb,
    const float* __restrict__ W1m, const float* __restrict__ b1v,
    const float* __restrict__ W2m, const float* __restrict__ b2v,
    const float* __restrict__ Wo, const float* __restrict__ bo,
    const float* __restrict__ h0f, const float* __restrict__ h1f,
    const float* __restrict__ c0s, const float* __restrict__ c1s,
    char* __restrict__ pb0, char* __restrict__ pb1,
    char* __restrict__ pv1, char* __restrict__ pv2,
    char* __restrict__ pv3, char* __restrict__ pv4,
    char* __restrict__ pbo, float* __restrict__ dout)
{
  __shared__ float vs[1024];
  __shared__ float vs2[1024];
  __shared__ float xsf[16];
  const int tid = threadIdx.x, b = blockIdx.x, wv = tid >> 6, lane = tid & 63;
  const int unit = (b << 2) + wv;
  float c0 = c0s[unit], c1 = c1s[unit];     // plain (prev dispatch)

  // prologue: seed pb0[0], pb1[0] with tag -1 (sc1 pairs)
  if (lane == 0) {
    st2c(pb0 + unit * 8, h0f[unit], -1);
    st2c(pb1 + unit * 8, h1f[unit], -1);
  }

  for (int s = 0; s < FUT; ++s) {
    const int cur = (s & 1) * 8192, nxt = ((s + 1) & 1) * 8192;
    // ---- P1: layer0 — needs pb0[cur] tag s-1, pbo tag s-1
    stage1024(pb0 + cur, s - 1, vs, wv, lane);
    if (tid < 15) {
      const char* p = pbo + tid * 8;
      i32x2 q;
      for (;;) {
        asm volatile("global_load_dwordx2 %0, %1, off sc1\n\ts_waitcnt vmcnt(0)"
                     : "=&v"(q) : "v"(p) : "memory");
        if (q.y == s - 1) break;
        __builtin_amdgcn_s_sleep(2);
      }
      xsf[tid] = __int_as_float(q.x);
    }
    __syncthreads();
    float a[4];
    #pragma unroll
    for (int g = 0; g < 4; ++g)
      a[g] = rowdot1024(Whh0 + (size_t)((g << 10) + unit) * 1024, vs, lane);
    {
      float gg[4];
      #pragma unroll
      for (int g = 0; g < 4; ++g) {
        int R = (g << 10) + unit;
        float s15 = 0.f;
        #pragma unroll
        for (int k = 0; k < 15; ++k) s15 = fmaf(Wih0[R * 15 + k], xsf[k], s15);
        gg[g] = a[g] + s15 + bih0[R] + bhh0[R];
      }
      float ii = sigm(gg[0]), ff = sigm(gg[1]), gv = tanhf(gg[2]), oo = sigm(gg[3]);
      c0 = ff * c0 + ii * gv;
      if (lane == 0) st2c(pb0 + nxt + unit * 8, oo * tanhf(c0), s);
    }
    // ---- P2: layer1 — needs pb0[nxt] tag s, pb1[cur] tag s-1
    stage1024(pb0 + nxt, s, vs, wv, lane);
    stage1024(pb1 + cur, s - 1, vs2, wv, lane);
    __syncthreads();
    #pragma unroll
    for (int g = 0; g < 4; ++g) {
      int R = (g << 10) + unit;
      float acc = 0.f;
      #pragma unroll
      for (int p = 0; p < 4; ++p) {
        int k = p * 256 + lane * 4;
        float4 w = *(const float4*)(Wih1 + (size_t)R * 1024 + k);
        float4 h = *(const float4*)(vs + k);
        acc = fmaf(w.x, h.x, acc); acc = fmaf(w.y, h.y, acc);
        acc = fmaf(w.z, h.z, acc); acc = fmaf(w.w, h.w, acc);
        float4 w2 = *(const float4*)(Whh1 + (size_t)R * 1024 + k);
        float4 h2 = *(const float4*)(vs2 + k);
        acc = fmaf(w2.x, h2.x, acc); acc = fmaf(w2.y, h2.y, acc);
        acc = fmaf(w2.z, h2.z, acc); acc = fmaf(w2.w, h2.w, acc);
      }
      #pragma unroll
      for (int off = 32; off; off >>= 1) acc += __shfl_xor(acc, off);
      a[g] = acc;
    }
    {
      float gg[4];
      #pragma unroll
      for (int g = 0; g < 4; ++g) { int R = (g << 10) + unit; gg[g] = a[g] + bih1[R] + bhh1[R]; }
      float ii = sigm(gg[0]), ff = sigm(gg[1]), gv = tanhf(gg[2]), oo = sigm(gg[3]);
      c1 = ff * c1 + ii * gv;
      if (lane == 0) st2c(pb1 + nxt + unit * 8, oo * tanhf(c1), s);
    }
    // ---- P3..P6: dense H->H layers (tag-chained pv buffers)
    {
      const char* vin[4] = {pb1 + nxt, pv1, pv2, pv3};
      const int vtag[4]  = {s, s, s, s};
      char* vo[4] = {pv1, pv2, pv3, pv4};
      #pragma unroll
      for (int l = 0; l < 4; ++l) {
        const float* Wd = (l == 0) ? linW : (l == 1) ? linW + 1048576 : (l == 2) ? W1m : W2m;
        const float* bd = (l == 0) ? linb : (l == 1) ? linb + 1024 : (l == 2) ? b1v : b2v;
        stage1024(vin[l], vtag[l], vs, wv, lane);
        __syncthreads();
        float acc = rowdot1024(Wd + (size_t)unit * 1024, vs, lane);
        if (lane == 0) st2c(vo[l] + unit * 8, leaky(acc + bd[unit]), s);
        __syncthreads();   // vs reused next iter; own-block stores done after reads
      }
    }
    // ---- P7: Wo head (block 0 only; others jump to next P1 poll)
    if (b == 0) {
      stage1024(pv4, s, vs, wv, lane);
      __syncthreads();
      for (int o = wv; o < 15; o += 4) {
        float acc = rowdot1024(Wo + (size_t)o * 1024, vs, lane);
        if (lane == 0) {
          float r = leaky(acc + bo[o]);
          dout[(8192 + s) * 15 + o] = r;     // plain (output)
          st2c(pbo + o * 8, r, s);           // tagged (next P1 gate)
        }
      }
      __syncthreads();
    }
  }
}

// ================= host =================
extern "C" void kernel_launch(void* const* d_in, const int* in_sizes, int n_in,
                              void* d_out, int out_size, void* d_ws, size_t ws_size,
                              hipStream_t stream)
{
  (void)in_sizes; (void)n_in; (void)out_size; (void)ws_size;
  const float* x    = (const float*)d_in[0];
  const float* Wih0 = (const float*)d_in[1];
  const float* Whh0 = (const float*)d_in[2];
  const float* bih0 = (const float*)d_in[3];
  const float* bhh0 = (const float*)d_in[4];
  const float* Wih1 = (const float*)d_in[5];
  const float* Whh1 = (const float*)d_in[6];
  const float* bih1 = (const float*)d_in[7];
  const float* bhh1 = (const float*)d_in[8];
  const float* linW = (const float*)d_in[9];
  const float* linb = (const float*)d_in[10];
  const float* W1m  = (const float*)d_in[11];
  const float* b1v  = (const float*)d_in[12];
  const float* W2m  = (const float*)d_in[13];
  const float* b2v  = (const float*)d_in[14];
  const float* Wo   = (const float*)d_in[15];
  const float* bo   = (const float*)d_in[16];
  float* dout = (float*)d_out;
  char*  ws   = (char*)d_ws;

  bfu*  hsbf = (bfu*)(ws);                             // 16 MB
  bfu*  ping = (bfu*)(ws + (size_t)16777216);          // 16 MB
  bfu*  wbf  = (bfu*)(ws + (size_t)33554432);          // 8 MB
  char* hrec = ws + (size_t)41943040;                  // 8 slots x 16 KB
  char* pb0  = hrec + 131072;                          // 2 x 8 KB
  char* pb1  = pb0 + 16384;                            // 2 x 8 KB
  char* pv1  = pb1 + 16384;                            // 8 KB each
  char* pv2  = pv1 + 8192;
  char* pv3  = pv2 + 8192;
  char* pv4  = pv3 + 8192;
  char* pbo  = pv4 + 8192;                             // 16 pairs
  float* c0s = (float*)(pbo + 256);
  float* c1s = c0s + 1024;
  float* h0f = c1s + 1024;
  float* h1f = h0f + 1024;
  // no memset needed: 0xAA poison is never a valid tag

  cast_w<<<dim3(4096), dim3(256), 0, stream>>>(linW, W1m, W2m, wbf);

  lstm_seq<<<dim3(256), dim3(256), 0, stream>>>(
      x, Wih0, Whh0, bih0, bhh0, Wih1, Whh1, bih1, bhh1,
      hsbf, hrec, c0s, c1s, h0f, h1f);

  dim3 gg(64, 8), bb(256);
  mlp_gemm<<<gg, bb, 0, stream>>>(hsbf, wbf,           linb,        ping);
  mlp_gemm<<<gg, bb, 0, stream>>>(ping, wbf + 1048576, linb + 1024, hsbf);
  mlp_gemm<<<gg, bb, 0, stream>>>(hsbf, wbf + 2097152, b1v,         ping);
  mlp_gemm<<<gg, bb, 0, stream>>>(ping, wbf + 3145728, b2v,         hsbf);

  wo_ker<<<dim3(512), dim3(256), 0, stream>>>(hsbf, Wo, bo, dout, pbo);

  future_seq<<<dim3(256), dim3(256), 0, stream>>>(
      Wih0, Whh0, bih0, bhh0, Wih1, Whh1, bih1, bhh1,
      linW, linb, W1m, b1v, W2m, b2v, Wo, bo,
      h0f, h1f, c0s, c1s, pb0, pb1, pv1, pv2, pv3, pv4, pbo, dout);
}